// Round 11
// baseline (1874.118 us; speedup 1.0000x reference)
//
#include <hip/hip_runtime.h>
#include <cstdint>

#define Tn 200
#define En 512

// L1-bypass L2-level 8B load (sc0): sees same-XCD write-through stores.
__device__ __forceinline__ unsigned long long l2_load(const unsigned long long* p) {
  unsigned long long v;
  asm volatile("global_load_dwordx2 %0, %1, off sc0\n\ts_waitcnt vmcnt(0)"
               : "=v"(v) : "v"(p) : "memory");
  return v;
}

// ---- embed gather for batch row 63 only ----
__global__ __launch_bounds__(128) void embed_k(const int* __restrict__ ids,
                                               const float* __restrict__ tab,
                                               float* __restrict__ x0) {
  const int t = blockIdx.x;
  const int e = threadIdx.x;
  const long id = ids[63 * Tn + t];
  const float4* src = (const float4*)(tab + (size_t)id * En);
  ((float4*)(x0 + (size_t)t * En))[e] = src[e];
}

// out[t][g] = (relu?)( A[t][:512] . W[g][:512] + bp1[g] + bp2?[g] )
__global__ __launch_bounds__(256) void gemm_rows(const float* __restrict__ A,
                                                 const float* __restrict__ W,
                                                 const float* __restrict__ bp1,
                                                 const float* __restrict__ bp2,
                                                 float* __restrict__ out,
                                                 int G, int relu) {
  __shared__ float xl[8 * 512];
  const int gr = blockIdx.x * 256 + threadIdx.x;
  const int t0 = blockIdx.y * 8;
  for (int i = threadIdx.x; i < 8 * 512; i += 256) xl[i] = A[(size_t)t0 * 512 + i];
  __syncthreads();
  const float b = bp1[gr] + (bp2 ? bp2[gr] : 0.f);
  float acc[8];
#pragma unroll
  for (int tt = 0; tt < 8; tt++) acc[tt] = b;
  const float4* wr = (const float4*)(W + (size_t)gr * 512);
  for (int k4 = 0; k4 < 128; k4++) {
    const float4 w = wr[k4];
#pragma unroll
    for (int tt = 0; tt < 8; tt++) {
      const float4 xv = *(const float4*)&xl[tt * 512 + k4 * 4];
      acc[tt] = fmaf(w.x, xv.x, fmaf(w.y, xv.y, fmaf(w.z, xv.z, fmaf(w.w, xv.w, acc[tt]))));
    }
  }
#pragma unroll
  for (int tt = 0; tt < 8; tt++) {
    float v = acc[tt];
    if (relu) v = fmaxf(v, 0.f);
    out[(size_t)(t0 + tt) * G + gr] = v;
  }
}

// ---- bidirectional LSTM recurrence: XCD-local L2 exchange, naked barrier ----
// Identical to R10 except two targeted poll-path changes:
//  (a) agent fallback every 32 misses (was 4): the every-4 LLC probe was a
//      blocking 400-900ns stall landing exactly at data-arrival time.
//  (b) producer issues the fast exf store BEFORE the slow exs store.
// Everything else: grid 128, workers b%8<2 pinned per-XCD by round-robin;
// 16 WGs x 512 thr/domain; naked lgkm-only barrier; producers never poll;
// 240 pollers poll 1 remote slot each; self-stage own elems; hcat epilogue.
__global__ __launch_bounds__(512, 2) void rec_k(const float* __restrict__ xp,   // [T][2048] fwd|bwd
                                                float* __restrict__ hcat,       // [T][512]
                                                unsigned long long* __restrict__ exf, // fast [T][512]
                                                unsigned long long* __restrict__ exs, // slow [T][512]
                                                const float* __restrict__ whh,  // dir-major 2*1024*256
                                                unsigned stampbase) {
  __shared__ __align__(16) float hs[2][288];  // stride-36 chunks, double buffer
  __shared__ float pad[21000];                // forces 1 WG/CU (>80KB total)
  const int b = blockIdx.x;
  const int dir = b & 7;
  if (dir > 1) return;                 // 32 worker blocks, 96 exit
  const int wg = b >> 3;               // 0..15
  const int tid = threadIdx.x;
  const int lane = tid & 63;
  const int row = tid >> 3, kc = tid & 7;
  const int elem = row >> 2, gate = row & 3;
  const int he = wg * 16 + elem;        // global h element [0,256)
  const int gr = gate * 256 + he;       // gate row (i|f|g|o blocks of 256)
  const float* whhD = whh + (size_t)dir * 262144;
  const float* xpD = xp + dir * 1024;

  if (stampbase == 0xDEADBEEFu) {  // never true at runtime; keeps pad live
    pad[tid] = xp[tid];
    hcat[tid] = pad[tid ^ 1];
  }

  float4 q0, q1, q2, q3, q4, q5, q6, q7;
  {
    const float4* p = (const float4*)(whhD + (size_t)gr * 256 + kc * 32);
    q0 = p[0]; q1 = p[1]; q2 = p[2]; q3 = p[3];
    q4 = p[4]; q5 = p[5]; q6 = p[6]; q7 = p[7];
  }
  for (int i = tid; i < 2 * 288; i += 512) ((float*)hs)[i] = 0.f;
  float c = 0.f;
  float xv = 0.f;
  if (kc == 0) xv = xpD[(size_t)(dir ? (Tn - 1) : 0) * 2048 + gr];
  const int isprod = ((lane & 31) == 0);   // tid%32==0: 16 producers
  const int base = lane & 32;
  // poller mapping: rank among non-producers; first 240 ranks poll the 240
  // remote slots (own-WG 16 slots are self-staged by producers).
  const int pr = tid - 1 - (tid >> 5);
  const int ispoll = (!isprod) && (pr < 240);
  const int slot = ispoll ? (pr + (pr >= wg * 16 ? 16 : 0)) : 0;
  const int coff = (slot >> 5) * 36 + (slot & 31);
  const int poff = (he >> 5) * 36 + (he & 31);
  __syncthreads();  // init barrier (full drain, once)

  for (int t = 0; t < Tn; ++t) {
    const int p = t & 1;
    // matvec on hs[p] = h(t-1)
    const float4* h4 = (const float4*)&hs[p][kc * 36];
    const float4 h0 = h4[0], h1 = h4[1], h2 = h4[2], h3 = h4[3];
    const float4 h5 = h4[4], h6 = h4[5], h7 = h4[6], h8 = h4[7];
    float a = 0.f;
    a = fmaf(q0.x, h0.x, a); a = fmaf(q0.y, h0.y, a); a = fmaf(q0.z, h0.z, a); a = fmaf(q0.w, h0.w, a);
    a = fmaf(q1.x, h1.x, a); a = fmaf(q1.y, h1.y, a); a = fmaf(q1.z, h1.z, a); a = fmaf(q1.w, h1.w, a);
    a = fmaf(q2.x, h2.x, a); a = fmaf(q2.y, h2.y, a); a = fmaf(q2.z, h2.z, a); a = fmaf(q2.w, h2.w, a);
    a = fmaf(q3.x, h3.x, a); a = fmaf(q3.y, h3.y, a); a = fmaf(q3.z, h3.z, a); a = fmaf(q3.w, h3.w, a);
    a = fmaf(q4.x, h5.x, a); a = fmaf(q4.y, h5.y, a); a = fmaf(q4.z, h5.z, a); a = fmaf(q4.w, h5.w, a);
    a = fmaf(q5.x, h6.x, a); a = fmaf(q5.y, h6.y, a); a = fmaf(q5.z, h6.z, a); a = fmaf(q5.w, h6.w, a);
    a = fmaf(q6.x, h7.x, a); a = fmaf(q6.y, h7.y, a); a = fmaf(q6.z, h7.z, a); a = fmaf(q6.w, h7.w, a);
    a = fmaf(q7.x, h8.x, a); a = fmaf(q7.y, h8.y, a); a = fmaf(q7.z, h8.z, a); a = fmaf(q7.w, h8.w, a);
    a += __shfl_xor(a, 1);
    a += __shfl_xor(a, 2);
    a += __shfl_xor(a, 4);
    // kc==0 roots: add xproj and apply this gate's activation in parallel
    if (kc == 0) {
      a += xv;
      const float sg = 1.f / (1.f + __expf(-a));
      const float th = 1.f - 2.f / (1.f + __expf(2.f * a));
      a = (gate == 2) ? th : sg;
    }
    // gather the 4 ACTIVATED gates of this wave's two elements to lanes 0/32
    const float gi = __shfl(a, base + 0);
    const float gf = __shfl(a, base + 8);
    const float gg = __shfl(a, base + 16);
    const float go = __shfl(a, base + 24);
    if (isprod) {
      c = gf * c + gi * gg;
      const float hv = go * (1.f - 2.f / (1.f + __expf(2.f * c)));
      const unsigned long long word =
          ((unsigned long long)(stampbase + t + 1) << 32) | __float_as_uint(hv);
      // fast word FIRST (critical path: XCD-L2 write-through), slow second
      __hip_atomic_store(&exf[(size_t)t * 512 + dir * 256 + he], word,
                         __ATOMIC_RELAXED, __HIP_MEMORY_SCOPE_WORKGROUP);
      __hip_atomic_store(&exs[(size_t)t * 512 + dir * 256 + he], word,
                         __ATOMIC_RELAXED, __HIP_MEMORY_SCOPE_AGENT);
      hs[p ^ 1][poff] = hv;  // self-stage own element
    } else if (ispoll && t + 1 < Tn) {
      const unsigned long long* fslot = &exf[(size_t)t * 512 + dir * 256 + slot];
      const unsigned long long* sslot = &exs[(size_t)t * 512 + dir * 256 + slot];
      const unsigned tgt = stampbase + (unsigned)t + 1u;
      unsigned long long v;
      int gd = 0, tot = 0;
      for (;;) {
        v = l2_load(fslot);                     // fast: same-XCD L2
        if ((unsigned)(v >> 32) == tgt) break;
        if (++gd >= 32) {                       // rare fallback: LLC probe
          gd = 0;
          v = __hip_atomic_load(sslot, __ATOMIC_RELAXED, __HIP_MEMORY_SCOPE_AGENT);
          if ((unsigned)(v >> 32) == tgt) break;
        }
        if (++tot >= (1 << 20)) break;
      }
      hs[p ^ 1][coff] = __uint_as_float((unsigned)v);
    }
    if (kc == 0 && t + 1 < Tn)  // xv prefetch AFTER poll; floats across barrier
      xv = xpD[(size_t)(dir ? (Tn - 2 - t) : (t + 1)) * 2048 + gr];
    // naked barrier: LDS ordering only, no vmcnt drain
    asm volatile("s_waitcnt lgkmcnt(0)\n\ts_barrier" ::: "memory");
  }

  // epilogue: write hcat from exf (own-WG words; own-CU L1/L2 visibility)
  __syncthreads();
  for (int i = tid; i < 16 * Tn; i += 512) {
    const int t = i >> 4, e2 = i & 15;
    const int h2 = wg * 16 + e2;
    const unsigned long long wv2 = exf[(size_t)t * 512 + dir * 256 + h2];
    const int rowt = dir ? (Tn - 1 - t) : t;
    hcat[(size_t)rowt * 512 + dir * 256 + h2] = __uint_as_float((unsigned)wv2);
  }
}

// ---- final 1024->7 matmul + softmax per timestep ----
__global__ __launch_bounds__(64) void mlp2_k(const float* __restrict__ h1,
                                             const float* __restrict__ w2,
                                             const float* __restrict__ b2,
                                             float* __restrict__ out) {
  __shared__ float hrow[1024];
  __shared__ float lg[8];
  const int t = blockIdx.x, tid = threadIdx.x;
  for (int i = tid; i < 1024; i += 64) hrow[i] = h1[(size_t)t * 1024 + i];
  __syncthreads();
  const int o = tid >> 3, kc = tid & 7;
  float acc = 0.f;
  if (o < 7) {
    const float* wv = w2 + (size_t)o * 1024 + kc * 128;
    const float* h = &hrow[kc * 128];
    for (int jj = 0; jj < 128; jj++) acc = fmaf(wv[jj], h[jj], acc);
  }
#pragma unroll
  for (int off = 1; off < 8; off <<= 1) acc += __shfl_xor(acc, off);
  if (o < 7 && kc == 0) lg[o] = acc + b2[o];
  __syncthreads();
  if (tid == 0) {
    float mx = -1e30f;
#pragma unroll
    for (int i = 0; i < 7; i++) mx = fmaxf(mx, lg[i]);
    float e[7];
    float s = 0.f;
#pragma unroll
    for (int i = 0; i < 7; i++) { e[i] = __expf(lg[i] - mx); s += e[i]; }
    const float inv = 1.f / s;
#pragma unroll
    for (int i = 0; i < 7; i++) out[t * 7 + i] = e[i] * inv;
  }
}

extern "C" void kernel_launch(void* const* d_in, const int* in_sizes, int n_in,
                              void* d_out, int out_size, void* d_ws, size_t ws_size,
                              hipStream_t stream) {
  const int* ids = (const int*)d_in[0];
  const float* tab = (const float*)d_in[1];
  const float* wih = (const float*)d_in[2];   // (2,2,1024,512)
  const float* whh = (const float*)d_in[3];   // (2,2,1024,256)
  const float* bih = (const float*)d_in[4];   // (2,2,1024)
  const float* bhh = (const float*)d_in[5];
  const float* w1 = (const float*)d_in[6];    // (1024,512)
  const float* b1 = (const float*)d_in[7];
  const float* w2 = (const float*)d_in[8];    // (7,1024)
  const float* b2 = (const float*)d_in[9];
  float* out = (float*)d_out;                 // (200,7) f32
  float* ws = (float*)d_ws;

  float* x0 = ws;                     // 200*512
  float* xp = ws + 102400;            // 200*2048 (reused both layers)
  float* h0 = ws + 512000;            // 200*512
  float* h1 = ws + 614400;            // 200*512
  float* hm = ws + 716800;            // 200*1024
  unsigned long long* exf = (unsigned long long*)(ws + 921600);   // fast slots
  unsigned long long* exs = exf + (size_t)Tn * 512;               // slow slots

  // clear stamps from previous replay (slots are write-once within a launch)
  hipMemsetAsync(exf, 0, (size_t)Tn * 512 * 8 * 2, stream);
  embed_k<<<Tn, 128, 0, stream>>>(ids, tab, x0);
  // layer 0
  gemm_rows<<<dim3(8, 25), 256, 0, stream>>>(x0, wih, bih, bhh, xp, 2048, 0);
  rec_k<<<128, 512, 0, stream>>>(xp, h0, exf, exs, whh, 0u);
  // layer 1 (shared ex buffers, disjoint stamp base)
  gemm_rows<<<dim3(8, 25), 256, 0, stream>>>(h0, wih + 1048576, bih + 2048, bhh + 2048, xp, 2048, 0);
  rec_k<<<128, 512, 0, stream>>>(xp, h1, exf, exs, whh + 524288, 1000000u);
  // MLP
  gemm_rows<<<dim3(4, 25), 256, 0, stream>>>(h1, w1, b1, nullptr, hm, 1024, 1);
  mlp2_k<<<Tn, 64, 0, stream>>>(hm, w2, b2, out);
}

// Round 12
// 1850.110 us; speedup vs baseline: 1.0130x; 1.0130x over previous
//
#include <hip/hip_runtime.h>
#include <cstdint>

#define Tn 200
#define En 512

// ---- embed gather for batch row 63 only ----
__global__ __launch_bounds__(128) void embed_k(const int* __restrict__ ids,
                                               const float* __restrict__ tab,
                                               float* __restrict__ x0) {
  const int t = blockIdx.x;
  const int e = threadIdx.x;
  const long id = ids[63 * Tn + t];
  const float4* src = (const float4*)(tab + (size_t)id * En);
  ((float4*)(x0 + (size_t)t * En))[e] = src[e];
}

// out[t][g] = (relu?)( A[t][:512] . W[g][:512] + bp1[g] + bp2?[g] )
__global__ __launch_bounds__(256) void gemm_rows(const float* __restrict__ A,
                                                 const float* __restrict__ W,
                                                 const float* __restrict__ bp1,
                                                 const float* __restrict__ bp2,
                                                 float* __restrict__ out,
                                                 int G, int relu) {
  __shared__ float xl[8 * 512];
  const int gr = blockIdx.x * 256 + threadIdx.x;
  const int t0 = blockIdx.y * 8;
  for (int i = threadIdx.x; i < 8 * 512; i += 256) xl[i] = A[(size_t)t0 * 512 + i];
  __syncthreads();
  const float b = bp1[gr] + (bp2 ? bp2[gr] : 0.f);
  float acc[8];
#pragma unroll
  for (int tt = 0; tt < 8; tt++) acc[tt] = b;
  const float4* wr = (const float4*)(W + (size_t)gr * 512);
  for (int k4 = 0; k4 < 128; k4++) {
    const float4 w = wr[k4];
#pragma unroll
    for (int tt = 0; tt < 8; tt++) {
      const float4 xv = *(const float4*)&xl[tt * 512 + k4 * 4];
      acc[tt] = fmaf(w.x, xv.x, fmaf(w.y, xv.y, fmaf(w.z, xv.z, fmaf(w.w, xv.w, acc[tt]))));
    }
  }
#pragma unroll
  for (int tt = 0; tt < 8; tt++) {
    float v = acc[tt];
    if (relu) v = fmaxf(v, 0.f);
    out[(size_t)(t0 + tt) * G + gr] = v;
  }
}

// ---- bidirectional LSTM recurrence: XCD-local L2 exchange via L1-invalidate ----
// R10 skeleton. The one structural change: the fast poll is a PLAIN
// (L1-cacheable) load spin with a periodic `buffer_inv sc0` (L1-only,
// per-CU invalidate). R9-R11 proved the sc0 load alone NEVER sees fresh
// data (it hits the consumer's own stale L1 line: sc0 = workgroup scope,
// L1-cached); the producer's write-through store has been sitting in the
// shared XCD L2 all along. Invalidate L1 -> next plain load refills from
// L2 -> detects in ~150-300ns with zero LLC traffic. Agent probes of exs
// remain the correctness fallback for wrong blockIdx->XCD placement
// (first at miss 24, then every 16 -- never on the fast path).
// hcat store returns to the producer (fire-and-forget under naked barrier;
// kernel-end flush makes it visible to the next kernel) -- no epilogue.
__global__ __launch_bounds__(512, 2) void rec_k(const float* __restrict__ xp,   // [T][2048] fwd|bwd
                                                float* __restrict__ hcat,       // [T][512]
                                                unsigned long long* __restrict__ exf, // fast [T][512]
                                                unsigned long long* __restrict__ exs, // slow [T][512]
                                                const float* __restrict__ whh,  // dir-major 2*1024*256
                                                unsigned stampbase) {
  __shared__ __align__(16) float hs[2][288];  // stride-36 chunks, double buffer
  __shared__ float pad[21000];                // forces 1 WG/CU (>80KB total)
  const int b = blockIdx.x;
  const int dir = b & 7;
  if (dir > 1) return;                 // 32 worker blocks, 96 exit
  const int wg = b >> 3;               // 0..15
  const int tid = threadIdx.x;
  const int lane = tid & 63;
  const int row = tid >> 3, kc = tid & 7;
  const int elem = row >> 2, gate = row & 3;
  const int he = wg * 16 + elem;        // global h element [0,256)
  const int gr = gate * 256 + he;       // gate row (i|f|g|o blocks of 256)
  const float* whhD = whh + (size_t)dir * 262144;
  const float* xpD = xp + dir * 1024;

  if (stampbase == 0xDEADBEEFu) {  // never true at runtime; keeps pad live
    pad[tid] = xp[tid];
    hcat[tid] = pad[tid ^ 1];
  }

  float4 q0, q1, q2, q3, q4, q5, q6, q7;
  {
    const float4* p = (const float4*)(whhD + (size_t)gr * 256 + kc * 32);
    q0 = p[0]; q1 = p[1]; q2 = p[2]; q3 = p[3];
    q4 = p[4]; q5 = p[5]; q6 = p[6]; q7 = p[7];
  }
  for (int i = tid; i < 2 * 288; i += 512) ((float*)hs)[i] = 0.f;
  float c = 0.f;
  float xv = 0.f;
  if (kc == 0) xv = xpD[(size_t)(dir ? (Tn - 1) : 0) * 2048 + gr];
  const int isprod = ((lane & 31) == 0);   // tid%32==0: 16 producers
  const int base = lane & 32;
  // poller mapping: rank among non-producers; first 240 ranks poll the 240
  // remote slots (own-WG 16 slots are self-staged by producers).
  const int pr = tid - 1 - (tid >> 5);
  const int ispoll = (!isprod) && (pr < 240);
  const int slot = ispoll ? (pr + (pr >= wg * 16 ? 16 : 0)) : 0;
  const int coff = (slot >> 5) * 36 + (slot & 31);
  const int poff = (he >> 5) * 36 + (he & 31);
  __syncthreads();  // init barrier (full drain, once)

  for (int t = 0; t < Tn; ++t) {
    const int p = t & 1;
    // matvec on hs[p] = h(t-1)
    const float4* h4 = (const float4*)&hs[p][kc * 36];
    const float4 h0 = h4[0], h1 = h4[1], h2 = h4[2], h3 = h4[3];
    const float4 h5 = h4[4], h6 = h4[5], h7 = h4[6], h8 = h4[7];
    float a = 0.f;
    a = fmaf(q0.x, h0.x, a); a = fmaf(q0.y, h0.y, a); a = fmaf(q0.z, h0.z, a); a = fmaf(q0.w, h0.w, a);
    a = fmaf(q1.x, h1.x, a); a = fmaf(q1.y, h1.y, a); a = fmaf(q1.z, h1.z, a); a = fmaf(q1.w, h1.w, a);
    a = fmaf(q2.x, h2.x, a); a = fmaf(q2.y, h2.y, a); a = fmaf(q2.z, h2.z, a); a = fmaf(q2.w, h2.w, a);
    a = fmaf(q3.x, h3.x, a); a = fmaf(q3.y, h3.y, a); a = fmaf(q3.z, h3.z, a); a = fmaf(q3.w, h3.w, a);
    a = fmaf(q4.x, h5.x, a); a = fmaf(q4.y, h5.y, a); a = fmaf(q4.z, h5.z, a); a = fmaf(q4.w, h5.w, a);
    a = fmaf(q5.x, h6.x, a); a = fmaf(q5.y, h6.y, a); a = fmaf(q5.z, h6.z, a); a = fmaf(q5.w, h6.w, a);
    a = fmaf(q6.x, h7.x, a); a = fmaf(q6.y, h7.y, a); a = fmaf(q6.z, h7.z, a); a = fmaf(q6.w, h7.w, a);
    a = fmaf(q7.x, h8.x, a); a = fmaf(q7.y, h8.y, a); a = fmaf(q7.z, h8.z, a); a = fmaf(q7.w, h8.w, a);
    a += __shfl_xor(a, 1);
    a += __shfl_xor(a, 2);
    a += __shfl_xor(a, 4);
    // kc==0 roots: add xproj and apply this gate's activation in parallel
    if (kc == 0) {
      a += xv;
      const float sg = 1.f / (1.f + __expf(-a));
      const float th = 1.f - 2.f / (1.f + __expf(2.f * a));
      a = (gate == 2) ? th : sg;
    }
    // gather the 4 ACTIVATED gates of this wave's two elements to lanes 0/32
    const float gi = __shfl(a, base + 0);
    const float gf = __shfl(a, base + 8);
    const float gg = __shfl(a, base + 16);
    const float go = __shfl(a, base + 24);
    if (isprod) {
      c = gf * c + gi * gg;
      const float hv = go * (1.f - 2.f / (1.f + __expf(2.f * c)));
      const unsigned long long word =
          ((unsigned long long)(stampbase + t + 1) << 32) | __float_as_uint(hv);
      // fast word FIRST: plain write-through -> lands in this XCD's L2
      __hip_atomic_store(&exf[(size_t)t * 512 + dir * 256 + he], word,
                         __ATOMIC_RELAXED, __HIP_MEMORY_SCOPE_WORKGROUP);
      // slow word: LLC-visible fallback for wrong-placement consumers
      __hip_atomic_store(&exs[(size_t)t * 512 + dir * 256 + he], word,
                         __ATOMIC_RELAXED, __HIP_MEMORY_SCOPE_AGENT);
      hs[p ^ 1][poff] = hv;  // self-stage own element
      const int rowt = dir ? (Tn - 1 - t) : t;
      hcat[(size_t)rowt * 512 + dir * 256 + he] = hv;  // fire-and-forget
    } else if (ispoll && t + 1 < Tn) {
      const unsigned long long* fslot = &exf[(size_t)t * 512 + dir * 256 + slot];
      const unsigned long long* sslot = &exs[(size_t)t * 512 + dir * 256 + slot];
      const unsigned tgt = stampbase + (unsigned)t + 1u;
      unsigned long long v;
      int tot = 0;
      for (;;) {
        // plain L1-cacheable load; freshness comes from the periodic L1 inv
        v = __hip_atomic_load(fslot, __ATOMIC_RELAXED, __HIP_MEMORY_SCOPE_WORKGROUP);
        if ((unsigned)(v >> 32) == tgt) break;
        ++tot;
        if ((tot & 7) == 0)  // dump own L1 -> next load refills from XCD L2
          asm volatile("buffer_inv sc0" ::: "memory");
        if ((tot & 15) == 8 && tot > 16) {  // rare LLC probe (placement fallback)
          v = __hip_atomic_load(sslot, __ATOMIC_RELAXED, __HIP_MEMORY_SCOPE_AGENT);
          if ((unsigned)(v >> 32) == tgt) break;
        }
        if (tot >= (1 << 20)) break;
      }
      hs[p ^ 1][coff] = __uint_as_float((unsigned)v);
    }
    if (kc == 0 && t + 1 < Tn)  // xv prefetch AFTER poll; floats across barrier
      xv = xpD[(size_t)(dir ? (Tn - 2 - t) : (t + 1)) * 2048 + gr];
    // naked barrier: LDS ordering only, no vmcnt drain
    asm volatile("s_waitcnt lgkmcnt(0)\n\ts_barrier" ::: "memory");
  }
}

// ---- final 1024->7 matmul + softmax per timestep ----
__global__ __launch_bounds__(64) void mlp2_k(const float* __restrict__ h1,
                                             const float* __restrict__ w2,
                                             const float* __restrict__ b2,
                                             float* __restrict__ out) {
  __shared__ float hrow[1024];
  __shared__ float lg[8];
  const int t = blockIdx.x, tid = threadIdx.x;
  for (int i = tid; i < 1024; i += 64) hrow[i] = h1[(size_t)t * 1024 + i];
  __syncthreads();
  const int o = tid >> 3, kc = tid & 7;
  float acc = 0.f;
  if (o < 7) {
    const float* wv = w2 + (size_t)o * 1024 + kc * 128;
    const float* h = &hrow[kc * 128];
    for (int jj = 0; jj < 128; jj++) acc = fmaf(wv[jj], h[jj], acc);
  }
#pragma unroll
  for (int off = 1; off < 8; off <<= 1) acc += __shfl_xor(acc, off);
  if (o < 7 && kc == 0) lg[o] = acc + b2[o];
  __syncthreads();
  if (tid == 0) {
    float mx = -1e30f;
#pragma unroll
    for (int i = 0; i < 7; i++) mx = fmaxf(mx, lg[i]);
    float e[7];
    float s = 0.f;
#pragma unroll
    for (int i = 0; i < 7; i++) { e[i] = __expf(lg[i] - mx); s += e[i]; }
    const float inv = 1.f / s;
#pragma unroll
    for (int i = 0; i < 7; i++) out[t * 7 + i] = e[i] * inv;
  }
}

extern "C" void kernel_launch(void* const* d_in, const int* in_sizes, int n_in,
                              void* d_out, int out_size, void* d_ws, size_t ws_size,
                              hipStream_t stream) {
  const int* ids = (const int*)d_in[0];
  const float* tab = (const float*)d_in[1];
  const float* wih = (const float*)d_in[2];   // (2,2,1024,512)
  const float* whh = (const float*)d_in[3];   // (2,2,1024,256)
  const float* bih = (const float*)d_in[4];   // (2,2,1024)
  const float* bhh = (const float*)d_in[5];
  const float* w1 = (const float*)d_in[6];    // (1024,512)
  const float* b1 = (const float*)d_in[7];
  const float* w2 = (const float*)d_in[8];    // (7,1024)
  const float* b2 = (const float*)d_in[9];
  float* out = (float*)d_out;                 // (200,7) f32
  float* ws = (float*)d_ws;

  float* x0 = ws;                     // 200*512
  float* xp = ws + 102400;            // 200*2048 (reused both layers)
  float* h0 = ws + 512000;            // 200*512
  float* h1 = ws + 614400;            // 200*512
  float* hm = ws + 716800;            // 200*1024
  unsigned long long* exf = (unsigned long long*)(ws + 921600);   // fast slots
  unsigned long long* exs = exf + (size_t)Tn * 512;               // slow slots

  // clear stamps from previous replay (slots are write-once within a launch)
  hipMemsetAsync(exf, 0, (size_t)Tn * 512 * 8 * 2, stream);
  embed_k<<<Tn, 128, 0, stream>>>(ids, tab, x0);
  // layer 0
  gemm_rows<<<dim3(8, 25), 256, 0, stream>>>(x0, wih, bih, bhh, xp, 2048, 0);
  rec_k<<<128, 512, 0, stream>>>(xp, h0, exf, exs, whh, 0u);
  // layer 1 (shared ex buffers, disjoint stamp base)
  gemm_rows<<<dim3(8, 25), 256, 0, stream>>>(h0, wih + 1048576, bih + 2048, bhh + 2048, xp, 2048, 0);
  rec_k<<<128, 512, 0, stream>>>(xp, h1, exf, exs, whh + 524288, 1000000u);
  // MLP
  gemm_rows<<<dim3(4, 25), 256, 0, stream>>>(h1, w1, b1, nullptr, hm, 1024, 1);
  mlp2_k<<<Tn, 64, 0, stream>>>(hm, w2, b2, out);
}

// Round 13
// 1040.948 us; speedup vs baseline: 1.8004x; 1.7773x over previous
//
#include <hip/hip_runtime.h>
#include <cstdint>

#define Tn 200
#define En 512

// ---- embed gather for batch row 63 only ----
__global__ __launch_bounds__(128) void embed_k(const int* __restrict__ ids,
                                               const float* __restrict__ tab,
                                               float* __restrict__ x0) {
  const int t = blockIdx.x;
  const int e = threadIdx.x;
  const long id = ids[63 * Tn + t];
  const float4* src = (const float4*)(tab + (size_t)id * En);
  ((float4*)(x0 + (size_t)t * En))[e] = src[e];
}

// out[t][g] = (relu?)( A[t][:512] . W[g][:512] + bp1[g] + bp2?[g] )
__global__ __launch_bounds__(256) void gemm_rows(const float* __restrict__ A,
                                                 const float* __restrict__ W,
                                                 const float* __restrict__ bp1,
                                                 const float* __restrict__ bp2,
                                                 float* __restrict__ out,
                                                 int G, int relu) {
  __shared__ float xl[8 * 512];
  const int gr = blockIdx.x * 256 + threadIdx.x;
  const int t0 = blockIdx.y * 8;
  for (int i = threadIdx.x; i < 8 * 512; i += 256) xl[i] = A[(size_t)t0 * 512 + i];
  __syncthreads();
  const float b = bp1[gr] + (bp2 ? bp2[gr] : 0.f);
  float acc[8];
#pragma unroll
  for (int tt = 0; tt < 8; tt++) acc[tt] = b;
  const float4* wr = (const float4*)(W + (size_t)gr * 512);
  for (int k4 = 0; k4 < 128; k4++) {
    const float4 w = wr[k4];
#pragma unroll
    for (int tt = 0; tt < 8; tt++) {
      const float4 xv = *(const float4*)&xl[tt * 512 + k4 * 4];
      acc[tt] = fmaf(w.x, xv.x, fmaf(w.y, xv.y, fmaf(w.z, xv.z, fmaf(w.w, xv.w, acc[tt]))));
    }
  }
#pragma unroll
  for (int tt = 0; tt < 8; tt++) {
    float v = acc[tt];
    if (relu) v = fmaxf(v, 0.f);
    out[(size_t)(t0 + tt) * G + gr] = v;
  }
}

// ---- bidirectional LSTM recurrence: consolidated proven-parts version ----
// R10 skeleton (naked lgkm-only barrier, producer/poller role split, xv
// prefetch after poll, 1 WG/CU LDS pad, fwd/bwd on disjoint block ranges)
// with the poll reduced to a PURE agent-scope atomic spin -- the only
// primitive that ever detected fresh data (R3/R10); all sc0 / buffer_inv
// "XCD-local" fast paths never fired once (R8-R12 monotone in agent-probe
// frequency). Single exchange buffer; producer = one agent store +
// LDS self-stage + fire-and-forget hcat store.
__global__ __launch_bounds__(512, 2) void rec_k(const float* __restrict__ xp,   // [T][2048] fwd|bwd
                                                float* __restrict__ hcat,       // [T][512]
                                                unsigned long long* __restrict__ ex, // [T][512]
                                                const float* __restrict__ whh,  // dir-major 2*1024*256
                                                unsigned stampbase) {
  __shared__ __align__(16) float hs[2][288];  // stride-36 chunks, double buffer
  __shared__ float pad[21000];                // forces 1 WG/CU (>80KB total)
  const int b = blockIdx.x;
  const int dir = b & 7;
  if (dir > 1) return;                 // 32 worker blocks, 96 exit
  const int wg = b >> 3;               // 0..15
  const int tid = threadIdx.x;
  const int lane = tid & 63;
  const int row = tid >> 3, kc = tid & 7;
  const int elem = row >> 2, gate = row & 3;
  const int he = wg * 16 + elem;        // global h element [0,256)
  const int gr = gate * 256 + he;       // gate row (i|f|g|o blocks of 256)
  const float* whhD = whh + (size_t)dir * 262144;
  const float* xpD = xp + dir * 1024;

  if (stampbase == 0xDEADBEEFu) {  // never true at runtime; keeps pad live
    pad[tid] = xp[tid];
    hcat[tid] = pad[tid ^ 1];
  }

  float4 q0, q1, q2, q3, q4, q5, q6, q7;
  {
    const float4* p = (const float4*)(whhD + (size_t)gr * 256 + kc * 32);
    q0 = p[0]; q1 = p[1]; q2 = p[2]; q3 = p[3];
    q4 = p[4]; q5 = p[5]; q6 = p[6]; q7 = p[7];
  }
  for (int i = tid; i < 2 * 288; i += 512) ((float*)hs)[i] = 0.f;
  float c = 0.f;
  float xv = 0.f;
  if (kc == 0) xv = xpD[(size_t)(dir ? (Tn - 1) : 0) * 2048 + gr];
  const int isprod = ((lane & 31) == 0);   // tid%32==0: 16 producers
  const int base = lane & 32;
  // poller mapping: rank among non-producers; first 240 ranks poll the 240
  // remote slots (own-WG 16 slots are self-staged by producers).
  const int pr = tid - 1 - (tid >> 5);
  const int ispoll = (!isprod) && (pr < 240);
  const int slot = ispoll ? (pr + (pr >= wg * 16 ? 16 : 0)) : 0;
  const int coff = (slot >> 5) * 36 + (slot & 31);
  const int poff = (he >> 5) * 36 + (he & 31);
  __syncthreads();  // init barrier (full drain, once)

  for (int t = 0; t < Tn; ++t) {
    const int p = t & 1;
    // matvec on hs[p] = h(t-1)
    const float4* h4 = (const float4*)&hs[p][kc * 36];
    const float4 h0 = h4[0], h1 = h4[1], h2 = h4[2], h3 = h4[3];
    const float4 h5 = h4[4], h6 = h4[5], h7 = h4[6], h8 = h4[7];
    float a = 0.f;
    a = fmaf(q0.x, h0.x, a); a = fmaf(q0.y, h0.y, a); a = fmaf(q0.z, h0.z, a); a = fmaf(q0.w, h0.w, a);
    a = fmaf(q1.x, h1.x, a); a = fmaf(q1.y, h1.y, a); a = fmaf(q1.z, h1.z, a); a = fmaf(q1.w, h1.w, a);
    a = fmaf(q2.x, h2.x, a); a = fmaf(q2.y, h2.y, a); a = fmaf(q2.z, h2.z, a); a = fmaf(q2.w, h2.w, a);
    a = fmaf(q3.x, h3.x, a); a = fmaf(q3.y, h3.y, a); a = fmaf(q3.z, h3.z, a); a = fmaf(q3.w, h3.w, a);
    a = fmaf(q4.x, h5.x, a); a = fmaf(q4.y, h5.y, a); a = fmaf(q4.z, h5.z, a); a = fmaf(q4.w, h5.w, a);
    a = fmaf(q5.x, h6.x, a); a = fmaf(q5.y, h6.y, a); a = fmaf(q5.z, h6.z, a); a = fmaf(q5.w, h6.w, a);
    a = fmaf(q6.x, h7.x, a); a = fmaf(q6.y, h7.y, a); a = fmaf(q6.z, h7.z, a); a = fmaf(q6.w, h7.w, a);
    a = fmaf(q7.x, h8.x, a); a = fmaf(q7.y, h8.y, a); a = fmaf(q7.z, h8.z, a); a = fmaf(q7.w, h8.w, a);
    a += __shfl_xor(a, 1);
    a += __shfl_xor(a, 2);
    a += __shfl_xor(a, 4);
    // kc==0 roots: add xproj and apply this gate's activation in parallel
    if (kc == 0) {
      a += xv;
      const float sg = 1.f / (1.f + __expf(-a));
      const float th = 1.f - 2.f / (1.f + __expf(2.f * a));
      a = (gate == 2) ? th : sg;
    }
    // gather the 4 ACTIVATED gates of this wave's two elements to lanes 0/32
    const float gi = __shfl(a, base + 0);
    const float gf = __shfl(a, base + 8);
    const float gg = __shfl(a, base + 16);
    const float go = __shfl(a, base + 24);
    if (isprod) {
      c = gf * c + gi * gg;
      const float hv = go * (1.f - 2.f / (1.f + __expf(2.f * c)));
      const unsigned long long word =
          ((unsigned long long)(stampbase + t + 1) << 32) | __float_as_uint(hv);
      // single agent store: LLC-visible to all pollers (fire-and-forget)
      __hip_atomic_store(&ex[(size_t)t * 512 + dir * 256 + he], word,
                         __ATOMIC_RELAXED, __HIP_MEMORY_SCOPE_AGENT);
      hs[p ^ 1][poff] = hv;  // self-stage own element
      const int rowt = dir ? (Tn - 1 - t) : t;
      hcat[(size_t)rowt * 512 + dir * 256 + he] = hv;  // fire-and-forget
    } else if (ispoll && t + 1 < Tn) {
      const unsigned long long* sl = &ex[(size_t)t * 512 + dir * 256 + slot];
      const unsigned tgt = stampbase + (unsigned)t + 1u;
      unsigned long long v;
      int tot = 0;
      do {  // pure agent spin: every probe is authoritative (proven R3/R10)
        v = __hip_atomic_load(sl, __ATOMIC_RELAXED, __HIP_MEMORY_SCOPE_AGENT);
      } while ((unsigned)(v >> 32) != tgt && ++tot < (1 << 20));
      hs[p ^ 1][coff] = __uint_as_float((unsigned)v);
    }
    if (kc == 0 && t + 1 < Tn)  // xv prefetch AFTER poll; floats across barrier
      xv = xpD[(size_t)(dir ? (Tn - 2 - t) : (t + 1)) * 2048 + gr];
    // naked barrier: LDS ordering only, no vmcnt drain
    asm volatile("s_waitcnt lgkmcnt(0)\n\ts_barrier" ::: "memory");
  }
}

// ---- final 1024->7 matmul + softmax per timestep ----
__global__ __launch_bounds__(64) void mlp2_k(const float* __restrict__ h1,
                                             const float* __restrict__ w2,
                                             const float* __restrict__ b2,
                                             float* __restrict__ out) {
  __shared__ float hrow[1024];
  __shared__ float lg[8];
  const int t = blockIdx.x, tid = threadIdx.x;
  for (int i = tid; i < 1024; i += 64) hrow[i] = h1[(size_t)t * 1024 + i];
  __syncthreads();
  const int o = tid >> 3, kc = tid & 7;
  float acc = 0.f;
  if (o < 7) {
    const float* wv = w2 + (size_t)o * 1024 + kc * 128;
    const float* h = &hrow[kc * 128];
    for (int jj = 0; jj < 128; jj++) acc = fmaf(wv[jj], h[jj], acc);
  }
#pragma unroll
  for (int off = 1; off < 8; off <<= 1) acc += __shfl_xor(acc, off);
  if (o < 7 && kc == 0) lg[o] = acc + b2[o];
  __syncthreads();
  if (tid == 0) {
    float mx = -1e30f;
#pragma unroll
    for (int i = 0; i < 7; i++) mx = fmaxf(mx, lg[i]);
    float e[7];
    float s = 0.f;
#pragma unroll
    for (int i = 0; i < 7; i++) { e[i] = __expf(lg[i] - mx); s += e[i]; }
    const float inv = 1.f / s;
#pragma unroll
    for (int i = 0; i < 7; i++) out[t * 7 + i] = e[i] * inv;
  }
}

extern "C" void kernel_launch(void* const* d_in, const int* in_sizes, int n_in,
                              void* d_out, int out_size, void* d_ws, size_t ws_size,
                              hipStream_t stream) {
  const int* ids = (const int*)d_in[0];
  const float* tab = (const float*)d_in[1];
  const float* wih = (const float*)d_in[2];   // (2,2,1024,512)
  const float* whh = (const float*)d_in[3];   // (2,2,1024,256)
  const float* bih = (const float*)d_in[4];   // (2,2,1024)
  const float* bhh = (const float*)d_in[5];
  const float* w1 = (const float*)d_in[6];    // (1024,512)
  const float* b1 = (const float*)d_in[7];
  const float* w2 = (const float*)d_in[8];    // (7,1024)
  const float* b2 = (const float*)d_in[9];
  float* out = (float*)d_out;                 // (200,7) f32
  float* ws = (float*)d_ws;

  float* x0 = ws;                     // 200*512
  float* xp = ws + 102400;            // 200*2048 (reused both layers)
  float* h0 = ws + 512000;            // 200*512
  float* h1 = ws + 614400;            // 200*512
  float* hm = ws + 716800;            // 200*1024
  unsigned long long* ex = (unsigned long long*)(ws + 921600);  // 200*512 slots

  // clear stamps from previous replay (slots are write-once within a launch)
  hipMemsetAsync(ex, 0, (size_t)Tn * 512 * 8, stream);
  embed_k<<<Tn, 128, 0, stream>>>(ids, tab, x0);
  // layer 0
  gemm_rows<<<dim3(8, 25), 256, 0, stream>>>(x0, wih, bih, bhh, xp, 2048, 0);
  rec_k<<<128, 512, 0, stream>>>(xp, h0, ex, whh, 0u);
  // layer 1 (shared ex buffer, disjoint stamp base)
  gemm_rows<<<dim3(8, 25), 256, 0, stream>>>(h0, wih + 1048576, bih + 2048, bhh + 2048, xp, 2048, 0);
  rec_k<<<128, 512, 0, stream>>>(xp, h1, ex, whh + 524288, 1000000u);
  // MLP
  gemm_rows<<<dim3(4, 25), 256, 0, stream>>>(h1, w1, b1, nullptr, hm, 1024, 1);
  mlp2_k<<<Tn, 64, 0, stream>>>(hm, w2, b2, out);
}

// Round 14
// 773.964 us; speedup vs baseline: 2.4215x; 1.3450x over previous
//
#include <hip/hip_runtime.h>
#include <cstdint>

#define Tn 200
#define En 512

// ---- embed gather for batch row 63 only ----
__global__ __launch_bounds__(128) void embed_k(const int* __restrict__ ids,
                                               const float* __restrict__ tab,
                                               float* __restrict__ x0) {
  const int t = blockIdx.x;
  const int e = threadIdx.x;
  const long id = ids[63 * Tn + t];
  const float4* src = (const float4*)(tab + (size_t)id * En);
  ((float4*)(x0 + (size_t)t * En))[e] = src[e];
}

// out[t][g] = (relu?)( A[t][:512] . W[g][:512] + bp1[g] + bp2?[g] )
__global__ __launch_bounds__(256) void gemm_rows(const float* __restrict__ A,
                                                 const float* __restrict__ W,
                                                 const float* __restrict__ bp1,
                                                 const float* __restrict__ bp2,
                                                 float* __restrict__ out,
                                                 int G, int relu) {
  __shared__ float xl[8 * 512];
  const int gr = blockIdx.x * 256 + threadIdx.x;
  const int t0 = blockIdx.y * 8;
  for (int i = threadIdx.x; i < 8 * 512; i += 256) xl[i] = A[(size_t)t0 * 512 + i];
  __syncthreads();
  const float b = bp1[gr] + (bp2 ? bp2[gr] : 0.f);
  float acc[8];
#pragma unroll
  for (int tt = 0; tt < 8; tt++) acc[tt] = b;
  const float4* wr = (const float4*)(W + (size_t)gr * 512);
  for (int k4 = 0; k4 < 128; k4++) {
    const float4 w = wr[k4];
#pragma unroll
    for (int tt = 0; tt < 8; tt++) {
      const float4 xv = *(const float4*)&xl[tt * 512 + k4 * 4];
      acc[tt] = fmaf(w.x, xv.x, fmaf(w.y, xv.y, fmaf(w.z, xv.z, fmaf(w.w, xv.w, acc[tt]))));
    }
  }
#pragma unroll
  for (int tt = 0; tt < 8; tt++) {
    float v = acc[tt];
    if (relu) v = fmaxf(v, 0.f);
    out[(size_t)(t0 + tt) * G + gr] = v;
  }
}

// ---- bidirectional LSTM recurrence: ELECTION-VERIFIED XCD-local exchange ----
// 256 blocks, 1/CU (84KB LDS pad) -> exactly 32 blocks per XCD. Each block
// reads HW_REG_XCC_ID (hardware truth, not the unverified blockIdx%8
// heuristic R8-R12 silently relied on) and ranks itself on its XCD via an
// atomic counter: XCC0 rank<16 -> fwd workers, XCC1 rank<16 -> bwd workers,
// all others exit. Both domains are guaranteed single-XCD, so the producer's
// write-through workgroup store lands in THE SAME L2 the consumers read.
// Poll: plain load; on miss `buffer_inv sc0` (drop own L1) + s_sleep, so the
// reload refills from the shared XCD L2; every 4th miss an agent probe of
// the exs copy (R10's proven cadence) -> worst case == R10, no deadlock.
__global__ __launch_bounds__(512, 2) void rec_k(const float* __restrict__ xp,   // [T][2048] fwd|bwd
                                                float* __restrict__ hcat,       // [T][512]
                                                unsigned long long* __restrict__ exf, // fast [T][512]
                                                unsigned long long* __restrict__ exs, // slow [T][512]
                                                unsigned* __restrict__ ectr,    // 16 u32, zeroed
                                                const float* __restrict__ whh,  // dir-major 2*1024*256
                                                unsigned stampbase) {
  __shared__ __align__(16) float hs[2][288];  // stride-36 chunks, double buffer
  __shared__ float pad[21000];                // forces 1 WG/CU (>80KB total)
  __shared__ int sel[2];                      // [xcc, rank]
  const int tid = threadIdx.x;
  if (stampbase == 0xDEADBEEFu) {  // never true at runtime; keeps pad live
    pad[tid] = xp[tid];
    hcat[tid] = pad[tid ^ 1];
  }
  // ---- election ----
  if (tid == 0) {
    unsigned xcc;
    asm volatile("s_getreg_b32 %0, hwreg(HW_REG_XCC_ID)" : "=s"(xcc));
    xcc &= 7u;
    const unsigned r = __hip_atomic_fetch_add(&ectr[xcc], 1u, __ATOMIC_RELAXED,
                                              __HIP_MEMORY_SCOPE_AGENT);
    sel[0] = (int)xcc;
    sel[1] = (int)r;
  }
  __syncthreads();
  const int xcc = sel[0], rank = sel[1];
  if (xcc > 1 || rank >= 16) return;   // 32 workers, 224 blocks exit
  const int dir = xcc;                 // XCC0 = fwd, XCC1 = bwd
  const int wg = rank;                 // 0..15

  const int lane = tid & 63;
  const int row = tid >> 3, kc = tid & 7;
  const int elem = row >> 2, gate = row & 3;
  const int he = wg * 16 + elem;        // global h element [0,256)
  const int gr = gate * 256 + he;       // gate row (i|f|g|o blocks of 256)
  const float* whhD = whh + (size_t)dir * 262144;
  const float* xpD = xp + dir * 1024;

  float4 q0, q1, q2, q3, q4, q5, q6, q7;
  {
    const float4* p = (const float4*)(whhD + (size_t)gr * 256 + kc * 32);
    q0 = p[0]; q1 = p[1]; q2 = p[2]; q3 = p[3];
    q4 = p[4]; q5 = p[5]; q6 = p[6]; q7 = p[7];
  }
  for (int i = tid; i < 2 * 288; i += 512) ((float*)hs)[i] = 0.f;
  float c = 0.f;
  float xv = 0.f;
  if (kc == 0) xv = xpD[(size_t)(dir ? (Tn - 1) : 0) * 2048 + gr];
  const int isprod = ((lane & 31) == 0);   // tid%32==0: 16 producers
  const int base = lane & 32;
  // poller mapping: rank among non-producers; first 240 ranks poll the 240
  // remote slots (own-WG 16 slots are self-staged by producers).
  const int pr = tid - 1 - (tid >> 5);
  const int ispoll = (!isprod) && (pr < 240);
  const int slot = ispoll ? (pr + (pr >= wg * 16 ? 16 : 0)) : 0;
  const int coff = (slot >> 5) * 36 + (slot & 31);
  const int poff = (he >> 5) * 36 + (he & 31);
  __syncthreads();  // init barrier (full drain, once)

  for (int t = 0; t < Tn; ++t) {
    const int p = t & 1;
    // matvec on hs[p] = h(t-1)
    const float4* h4 = (const float4*)&hs[p][kc * 36];
    const float4 h0 = h4[0], h1 = h4[1], h2 = h4[2], h3 = h4[3];
    const float4 h5 = h4[4], h6 = h4[5], h7 = h4[6], h8 = h4[7];
    float a = 0.f;
    a = fmaf(q0.x, h0.x, a); a = fmaf(q0.y, h0.y, a); a = fmaf(q0.z, h0.z, a); a = fmaf(q0.w, h0.w, a);
    a = fmaf(q1.x, h1.x, a); a = fmaf(q1.y, h1.y, a); a = fmaf(q1.z, h1.z, a); a = fmaf(q1.w, h1.w, a);
    a = fmaf(q2.x, h2.x, a); a = fmaf(q2.y, h2.y, a); a = fmaf(q2.z, h2.z, a); a = fmaf(q2.w, h2.w, a);
    a = fmaf(q3.x, h3.x, a); a = fmaf(q3.y, h3.y, a); a = fmaf(q3.z, h3.z, a); a = fmaf(q3.w, h3.w, a);
    a = fmaf(q4.x, h5.x, a); a = fmaf(q4.y, h5.y, a); a = fmaf(q4.z, h5.z, a); a = fmaf(q4.w, h5.w, a);
    a = fmaf(q5.x, h6.x, a); a = fmaf(q5.y, h6.y, a); a = fmaf(q5.z, h6.z, a); a = fmaf(q5.w, h6.w, a);
    a = fmaf(q6.x, h7.x, a); a = fmaf(q6.y, h7.y, a); a = fmaf(q6.z, h7.z, a); a = fmaf(q6.w, h7.w, a);
    a = fmaf(q7.x, h8.x, a); a = fmaf(q7.y, h8.y, a); a = fmaf(q7.z, h8.z, a); a = fmaf(q7.w, h8.w, a);
    a += __shfl_xor(a, 1);
    a += __shfl_xor(a, 2);
    a += __shfl_xor(a, 4);
    // kc==0 roots: add xproj and apply this gate's activation in parallel
    if (kc == 0) {
      a += xv;
      const float sg = 1.f / (1.f + __expf(-a));
      const float th = 1.f - 2.f / (1.f + __expf(2.f * a));
      a = (gate == 2) ? th : sg;
    }
    // gather the 4 ACTIVATED gates of this wave's two elements to lanes 0/32
    const float gi = __shfl(a, base + 0);
    const float gf = __shfl(a, base + 8);
    const float gg = __shfl(a, base + 16);
    const float go = __shfl(a, base + 24);
    if (isprod) {
      c = gf * c + gi * gg;
      const float hv = go * (1.f - 2.f / (1.f + __expf(2.f * c)));
      const unsigned long long word =
          ((unsigned long long)(stampbase + t + 1) << 32) | __float_as_uint(hv);
      // fast word FIRST: write-through -> shared XCD L2 (same L2 as pollers)
      __hip_atomic_store(&exf[(size_t)t * 512 + dir * 256 + he], word,
                         __ATOMIC_RELAXED, __HIP_MEMORY_SCOPE_WORKGROUP);
      // slow word: LLC-visible fallback (guarantees progress regardless)
      __hip_atomic_store(&exs[(size_t)t * 512 + dir * 256 + he], word,
                         __ATOMIC_RELAXED, __HIP_MEMORY_SCOPE_AGENT);
      hs[p ^ 1][poff] = hv;  // self-stage own element
    } else if (ispoll && t + 1 < Tn) {
      const unsigned long long* fslot = &exf[(size_t)t * 512 + dir * 256 + slot];
      const unsigned long long* sslot = &exs[(size_t)t * 512 + dir * 256 + slot];
      const unsigned tgt = stampbase + (unsigned)t + 1u;
      unsigned long long v;
      int tot = 0;
      for (;;) {
        v = __hip_atomic_load(fslot, __ATOMIC_RELAXED, __HIP_MEMORY_SCOPE_WORKGROUP);
        if ((unsigned)(v >> 32) == tgt) break;
        // drop own L1 so the next plain load refills from the shared XCD L2
        asm volatile("buffer_inv sc0" ::: "memory");
        asm volatile("s_sleep 1");
        if (((++tot) & 3) == 0) {               // R10 cadence: LLC probe
          v = __hip_atomic_load(sslot, __ATOMIC_RELAXED, __HIP_MEMORY_SCOPE_AGENT);
          if ((unsigned)(v >> 32) == tgt) break;
        }
        if (tot >= (1 << 20)) break;
      }
      hs[p ^ 1][coff] = __uint_as_float((unsigned)v);
    }
    if (kc == 0 && t + 1 < Tn)  // xv prefetch AFTER poll; floats across barrier
      xv = xpD[(size_t)(dir ? (Tn - 2 - t) : (t + 1)) * 2048 + gr];
    // naked barrier: LDS ordering only, no vmcnt drain
    asm volatile("s_waitcnt lgkmcnt(0)\n\ts_barrier" ::: "memory");
  }

  // epilogue: write hcat from exf (own-WG words; same-CU visibility)
  __syncthreads();
  for (int i = tid; i < 16 * Tn; i += 512) {
    const int t = i >> 4, e2 = i & 15;
    const int h2 = wg * 16 + e2;
    const unsigned long long wv2 = exf[(size_t)t * 512 + dir * 256 + h2];
    const int rowt = dir ? (Tn - 1 - t) : t;
    hcat[(size_t)rowt * 512 + dir * 256 + h2] = __uint_as_float((unsigned)wv2);
  }
}

// ---- final 1024->7 matmul + softmax per timestep ----
__global__ __launch_bounds__(64) void mlp2_k(const float* __restrict__ h1,
                                             const float* __restrict__ w2,
                                             const float* __restrict__ b2,
                                             float* __restrict__ out) {
  __shared__ float hrow[1024];
  __shared__ float lg[8];
  const int t = blockIdx.x, tid = threadIdx.x;
  for (int i = tid; i < 1024; i += 64) hrow[i] = h1[(size_t)t * 1024 + i];
  __syncthreads();
  const int o = tid >> 3, kc = tid & 7;
  float acc = 0.f;
  if (o < 7) {
    const float* wv = w2 + (size_t)o * 1024 + kc * 128;
    const float* h = &hrow[kc * 128];
    for (int jj = 0; jj < 128; jj++) acc = fmaf(wv[jj], h[jj], acc);
  }
#pragma unroll
  for (int off = 1; off < 8; off <<= 1) acc += __shfl_xor(acc, off);
  if (o < 7 && kc == 0) lg[o] = acc + b2[o];
  __syncthreads();
  if (tid == 0) {
    float mx = -1e30f;
#pragma unroll
    for (int i = 0; i < 7; i++) mx = fmaxf(mx, lg[i]);
    float e[7];
    float s = 0.f;
#pragma unroll
    for (int i = 0; i < 7; i++) { e[i] = __expf(lg[i] - mx); s += e[i]; }
    const float inv = 1.f / s;
#pragma unroll
    for (int i = 0; i < 7; i++) out[t * 7 + i] = e[i] * inv;
  }
}

extern "C" void kernel_launch(void* const* d_in, const int* in_sizes, int n_in,
                              void* d_out, int out_size, void* d_ws, size_t ws_size,
                              hipStream_t stream) {
  const int* ids = (const int*)d_in[0];
  const float* tab = (const float*)d_in[1];
  const float* wih = (const float*)d_in[2];   // (2,2,1024,512)
  const float* whh = (const float*)d_in[3];   // (2,2,1024,256)
  const float* bih = (const float*)d_in[4];   // (2,2,1024)
  const float* bhh = (const float*)d_in[5];
  const float* w1 = (const float*)d_in[6];    // (1024,512)
  const float* b1 = (const float*)d_in[7];
  const float* w2 = (const float*)d_in[8];    // (7,1024)
  const float* b2 = (const float*)d_in[9];
  float* out = (float*)d_out;                 // (200,7) f32
  float* ws = (float*)d_ws;

  float* x0 = ws;                     // 200*512
  float* xp = ws + 102400;            // 200*2048 (reused both layers)
  float* h0 = ws + 512000;            // 200*512
  float* h1 = ws + 614400;            // 200*512
  float* hm = ws + 716800;            // 200*1024
  unsigned long long* exf = (unsigned long long*)(ws + 921600);   // fast slots
  unsigned long long* exs = exf + (size_t)Tn * 512;               // slow slots
  unsigned* ectr = (unsigned*)(exs + (size_t)Tn * 512);           // 2x16 u32

  // clear stamps + election counters (slots write-once within a launch)
  hipMemsetAsync(exf, 0, (size_t)Tn * 512 * 8 * 2 + 128, stream);
  embed_k<<<Tn, 128, 0, stream>>>(ids, tab, x0);
  // layer 0
  gemm_rows<<<dim3(8, 25), 256, 0, stream>>>(x0, wih, bih, bhh, xp, 2048, 0);
  rec_k<<<256, 512, 0, stream>>>(xp, h0, exf, exs, ectr, whh, 0u);
  // layer 1 (shared ex buffers, disjoint stamp base + fresh counters)
  gemm_rows<<<dim3(8, 25), 256, 0, stream>>>(h0, wih + 1048576, bih + 2048, bhh + 2048, xp, 2048, 0);
  rec_k<<<256, 512, 0, stream>>>(xp, h1, exf, exs, ectr + 16, whh + 524288, 1000000u);
  // MLP
  gemm_rows<<<dim3(4, 25), 256, 0, stream>>>(h1, w1, b1, nullptr, hm, 1024, 1);
  mlp2_k<<<Tn, 64, 0, stream>>>(hm, w2, b2, out);
}

// Round 15
// 590.319 us; speedup vs baseline: 3.1748x; 1.3111x over previous
//
#include <hip/hip_runtime.h>
#include <cstdint>

#define Tn 200
#define En 512

// ---- embed gather for batch row 63 only ----
__global__ __launch_bounds__(128) void embed_k(const int* __restrict__ ids,
                                               const float* __restrict__ tab,
                                               float* __restrict__ x0) {
  const int t = blockIdx.x;
  const int e = threadIdx.x;
  const long id = ids[63 * Tn + t];
  const float4* src = (const float4*)(tab + (size_t)id * En);
  ((float4*)(x0 + (size_t)t * En))[e] = src[e];
}

// out[t][g] = (relu?)( A[t][:512] . W[g][:512] + bp1[g] + bp2?[g] )
__global__ __launch_bounds__(256) void gemm_rows(const float* __restrict__ A,
                                                 const float* __restrict__ W,
                                                 const float* __restrict__ bp1,
                                                 const float* __restrict__ bp2,
                                                 float* __restrict__ out,
                                                 int G, int relu) {
  __shared__ float xl[8 * 512];
  const int gr = blockIdx.x * 256 + threadIdx.x;
  const int t0 = blockIdx.y * 8;
  for (int i = threadIdx.x; i < 8 * 512; i += 256) xl[i] = A[(size_t)t0 * 512 + i];
  __syncthreads();
  const float b = bp1[gr] + (bp2 ? bp2[gr] : 0.f);
  float acc[8];
#pragma unroll
  for (int tt = 0; tt < 8; tt++) acc[tt] = b;
  const float4* wr = (const float4*)(W + (size_t)gr * 512);
  for (int k4 = 0; k4 < 128; k4++) {
    const float4 w = wr[k4];
#pragma unroll
    for (int tt = 0; tt < 8; tt++) {
      const float4 xv = *(const float4*)&xl[tt * 512 + k4 * 4];
      acc[tt] = fmaf(w.x, xv.x, fmaf(w.y, xv.y, fmaf(w.z, xv.z, fmaf(w.w, xv.w, acc[tt]))));
    }
  }
#pragma unroll
  for (int tt = 0; tt < 8; tt++) {
    float v = acc[tt];
    if (relu) v = fmaxf(v, 0.f);
    out[(size_t)(t0 + tt) * G + gr] = v;
  }
}

// ---- bidirectional LSTM recurrence: R10 skeleton + paced pair-polling ----
// Grid 128; workers b&7==0 (fwd) / ==1 (bwd); 16 WGs x 512 thr per domain,
// LDS pad -> 1 WG/CU. Exchange is agent/LLC-only (R8-R14 proved no faster
// HIP-expressible path exists). Changes vs R10, ALL in the poll path:
//  - pair-polling: 120 pollers/WG, each owns 2 adjacent slots read by ONE
//    global_load_dwordx4 sc0 sc1 (both stamp|data words) -> probe message
//    count halved vs R10, quartered vs R13's storm.
//  - sleep pacing: s_sleep 12 (~320ns) before first probe (probe lands at
//    LLC right as producer visibility arrives), s_sleep 6 between retries.
//    Replaces R10's 4 wasted sc0 spacer loads with zero-traffic waits.
//  - single ex buffer / single agent store (less store-queue pressure).
// Keep: naked lgkm barrier, producers never poll, xv prefetch after poll,
// self-stage, fire-and-forget hcat.
__global__ __launch_bounds__(512, 2) void rec_k(const float* __restrict__ xp,   // [T][2048] fwd|bwd
                                                float* __restrict__ hcat,       // [T][512]
                                                unsigned long long* __restrict__ ex, // [T][512]
                                                const float* __restrict__ whh,  // dir-major 2*1024*256
                                                unsigned stampbase) {
  __shared__ __align__(16) float hs[2][288];  // stride-36 chunks, double buffer
  __shared__ float pad[21000];                // forces 1 WG/CU (>80KB total)
  const int b = blockIdx.x;
  const int dir = b & 7;
  if (dir > 1) return;                 // 32 worker blocks, 96 exit
  const int wg = b >> 3;               // 0..15
  const int tid = threadIdx.x;
  const int lane = tid & 63;
  const int row = tid >> 3, kc = tid & 7;
  const int elem = row >> 2, gate = row & 3;
  const int he = wg * 16 + elem;        // global h element [0,256)
  const int gr = gate * 256 + he;       // gate row (i|f|g|o blocks of 256)
  const float* whhD = whh + (size_t)dir * 262144;
  const float* xpD = xp + dir * 1024;

  if (stampbase == 0xDEADBEEFu) {  // never true at runtime; keeps pad live
    pad[tid] = xp[tid];
    hcat[tid] = pad[tid ^ 1];
  }

  float4 q0, q1, q2, q3, q4, q5, q6, q7;
  {
    const float4* p = (const float4*)(whhD + (size_t)gr * 256 + kc * 32);
    q0 = p[0]; q1 = p[1]; q2 = p[2]; q3 = p[3];
    q4 = p[4]; q5 = p[5]; q6 = p[6]; q7 = p[7];
  }
  for (int i = tid; i < 2 * 288; i += 512) ((float*)hs)[i] = 0.f;
  float c = 0.f;
  float xv = 0.f;
  if (kc == 0) xv = xpD[(size_t)(dir ? (Tn - 1) : 0) * 2048 + gr];
  const int isprod = ((lane & 31) == 0);   // tid%32==0: 16 producers
  const int base = lane & 32;
  // pair-poller mapping: rank among non-producers; first 120 ranks poll the
  // 120 remote slot-PAIRS (own-WG 8 pairs self-staged by producers).
  const int pr = tid - 1 - (tid >> 5);
  const int ispoll = (!isprod) && (pr < 120);
  const int pairIdx = ispoll ? (pr + (pr >= wg * 8 ? 8 : 0)) : 0;
  const int s0 = 2 * pairIdx;                          // first slot of pair
  const int coff2 = (s0 >> 5) * 36 + (s0 & 31);        // both floats land here,+1
  const int poff = (he >> 5) * 36 + (he & 31);
  __syncthreads();  // init barrier (full drain, once)

  for (int t = 0; t < Tn; ++t) {
    const int p = t & 1;
    // matvec on hs[p] = h(t-1)
    const float4* h4 = (const float4*)&hs[p][kc * 36];
    const float4 h0 = h4[0], h1 = h4[1], h2 = h4[2], h3 = h4[3];
    const float4 h5 = h4[4], h6 = h4[5], h7 = h4[6], h8 = h4[7];
    float a = 0.f;
    a = fmaf(q0.x, h0.x, a); a = fmaf(q0.y, h0.y, a); a = fmaf(q0.z, h0.z, a); a = fmaf(q0.w, h0.w, a);
    a = fmaf(q1.x, h1.x, a); a = fmaf(q1.y, h1.y, a); a = fmaf(q1.z, h1.z, a); a = fmaf(q1.w, h1.w, a);
    a = fmaf(q2.x, h2.x, a); a = fmaf(q2.y, h2.y, a); a = fmaf(q2.z, h2.z, a); a = fmaf(q2.w, h2.w, a);
    a = fmaf(q3.x, h3.x, a); a = fmaf(q3.y, h3.y, a); a = fmaf(q3.z, h3.z, a); a = fmaf(q3.w, h3.w, a);
    a = fmaf(q4.x, h5.x, a); a = fmaf(q4.y, h5.y, a); a = fmaf(q4.z, h5.z, a); a = fmaf(q4.w, h5.w, a);
    a = fmaf(q5.x, h6.x, a); a = fmaf(q5.y, h6.y, a); a = fmaf(q5.z, h6.z, a); a = fmaf(q5.w, h6.w, a);
    a = fmaf(q6.x, h7.x, a); a = fmaf(q6.y, h7.y, a); a = fmaf(q6.z, h7.z, a); a = fmaf(q6.w, h7.w, a);
    a = fmaf(q7.x, h8.x, a); a = fmaf(q7.y, h8.y, a); a = fmaf(q7.z, h8.z, a); a = fmaf(q7.w, h8.w, a);
    a += __shfl_xor(a, 1);
    a += __shfl_xor(a, 2);
    a += __shfl_xor(a, 4);
    // kc==0 roots: add xproj and apply this gate's activation in parallel
    if (kc == 0) {
      a += xv;
      const float sg = 1.f / (1.f + __expf(-a));
      const float th = 1.f - 2.f / (1.f + __expf(2.f * a));
      a = (gate == 2) ? th : sg;
    }
    // gather the 4 ACTIVATED gates of this wave's two elements to lanes 0/32
    const float gi = __shfl(a, base + 0);
    const float gf = __shfl(a, base + 8);
    const float gg = __shfl(a, base + 16);
    const float go = __shfl(a, base + 24);
    if (isprod) {
      c = gf * c + gi * gg;
      const float hv = go * (1.f - 2.f / (1.f + __expf(2.f * c)));
      const unsigned long long word =
          ((unsigned long long)(stampbase + t + 1) << 32) | __float_as_uint(hv);
      // single agent store (fire-and-forget; ack floats across naked barrier)
      __hip_atomic_store(&ex[(size_t)t * 512 + dir * 256 + he], word,
                         __ATOMIC_RELAXED, __HIP_MEMORY_SCOPE_AGENT);
      hs[p ^ 1][poff] = hv;  // self-stage own element
      const int rowt = dir ? (Tn - 1 - t) : t;
      hcat[(size_t)rowt * 512 + dir * 256 + he] = hv;  // fire-and-forget
    } else if (ispoll && t + 1 < Tn) {
      const unsigned long long* pp = &ex[(size_t)t * 512 + dir * 256 + s0];
      const unsigned tgt = stampbase + (unsigned)t + 1u;
      typedef unsigned int u32x4 __attribute__((ext_vector_type(4)));
      u32x4 v;
      int tot = 0;
      asm volatile("s_sleep 12");   // ~320ns: probe arrives as data becomes visible
      for (;;) {
        asm volatile("global_load_dwordx4 %0, %1, off sc0 sc1\n\ts_waitcnt vmcnt(0)"
                     : "=v"(v) : "v"(pp) : "memory");
        if (v.y == tgt && v.w == tgt) break;   // both pair stamps fresh
        if (++tot >= (1 << 18)) break;
        asm volatile("s_sleep 6");  // ~160ns pacing between probes
      }
      hs[p ^ 1][coff2]     = __uint_as_float(v.x);
      hs[p ^ 1][coff2 + 1] = __uint_as_float(v.z);
    }
    if (kc == 0 && t + 1 < Tn)  // xv prefetch AFTER poll; floats across barrier
      xv = xpD[(size_t)(dir ? (Tn - 2 - t) : (t + 1)) * 2048 + gr];
    // naked barrier: LDS ordering only, no vmcnt drain
    asm volatile("s_waitcnt lgkmcnt(0)\n\ts_barrier" ::: "memory");
  }
}

// ---- final 1024->7 matmul + softmax per timestep ----
__global__ __launch_bounds__(64) void mlp2_k(const float* __restrict__ h1,
                                             const float* __restrict__ w2,
                                             const float* __restrict__ b2,
                                             float* __restrict__ out) {
  __shared__ float hrow[1024];
  __shared__ float lg[8];
  const int t = blockIdx.x, tid = threadIdx.x;
  for (int i = tid; i < 1024; i += 64) hrow[i] = h1[(size_t)t * 1024 + i];
  __syncthreads();
  const int o = tid >> 3, kc = tid & 7;
  float acc = 0.f;
  if (o < 7) {
    const float* wv = w2 + (size_t)o * 1024 + kc * 128;
    const float* h = &hrow[kc * 128];
    for (int jj = 0; jj < 128; jj++) acc = fmaf(wv[jj], h[jj], acc);
  }
#pragma unroll
  for (int off = 1; off < 8; off <<= 1) acc += __shfl_xor(acc, off);
  if (o < 7 && kc == 0) lg[o] = acc + b2[o];
  __syncthreads();
  if (tid == 0) {
    float mx = -1e30f;
#pragma unroll
    for (int i = 0; i < 7; i++) mx = fmaxf(mx, lg[i]);
    float e[7];
    float s = 0.f;
#pragma unroll
    for (int i = 0; i < 7; i++) { e[i] = __expf(lg[i] - mx); s += e[i]; }
    const float inv = 1.f / s;
#pragma unroll
    for (int i = 0; i < 7; i++) out[t * 7 + i] = e[i] * inv;
  }
}

extern "C" void kernel_launch(void* const* d_in, const int* in_sizes, int n_in,
                              void* d_out, int out_size, void* d_ws, size_t ws_size,
                              hipStream_t stream) {
  const int* ids = (const int*)d_in[0];
  const float* tab = (const float*)d_in[1];
  const float* wih = (const float*)d_in[2];   // (2,2,1024,512)
  const float* whh = (const float*)d_in[3];   // (2,2,1024,256)
  const float* bih = (const float*)d_in[4];   // (2,2,1024)
  const float* bhh = (const float*)d_in[5];
  const float* w1 = (const float*)d_in[6];    // (1024,512)
  const float* b1 = (const float*)d_in[7];
  const float* w2 = (const float*)d_in[8];    // (7,1024)
  const float* b2 = (const float*)d_in[9];
  float* out = (float*)d_out;                 // (200,7) f32
  float* ws = (float*)d_ws;

  float* x0 = ws;                     // 200*512
  float* xp = ws + 102400;            // 200*2048 (reused both layers)
  float* h0 = ws + 512000;            // 200*512
  float* h1 = ws + 614400;            // 200*512
  float* hm = ws + 716800;            // 200*1024
  unsigned long long* ex = (unsigned long long*)(ws + 921600);  // 200*512 slots

  // clear stamps from previous replay (slots are write-once within a launch)
  hipMemsetAsync(ex, 0, (size_t)Tn * 512 * 8, stream);
  embed_k<<<Tn, 128, 0, stream>>>(ids, tab, x0);
  // layer 0
  gemm_rows<<<dim3(8, 25), 256, 0, stream>>>(x0, wih, bih, bhh, xp, 2048, 0);
  rec_k<<<128, 512, 0, stream>>>(xp, h0, ex, whh, 0u);
  // layer 1 (shared ex buffer, disjoint stamp base)
  gemm_rows<<<dim3(8, 25), 256, 0, stream>>>(h0, wih + 1048576, bih + 2048, bhh + 2048, xp, 2048, 0);
  rec_k<<<128, 512, 0, stream>>>(xp, h1, ex, whh + 524288, 1000000u);
  // MLP
  gemm_rows<<<dim3(4, 25), 256, 0, stream>>>(h1, w1, b1, nullptr, hm, 1024, 1);
  mlp2_k<<<Tn, 64, 0, stream>>>(hm, w2, b2, out);
}

// Round 16
// 555.332 us; speedup vs baseline: 3.3748x; 1.0630x over previous
//
#include <hip/hip_runtime.h>
#include <cstdint>

#define Tn 200
#define En 512

// out[t][g] = (relu?)( A[t][:512] . W[g][:512] + bp1[g] + bp2?[g] )
// If ids!=nullptr, row t of A is tab[ids[63*Tn+t]] (fused embed gather).
__global__ __launch_bounds__(256) void gemm_rows(const float* __restrict__ A,
                                                 const int* __restrict__ ids,
                                                 const float* __restrict__ tab,
                                                 const float* __restrict__ W,
                                                 const float* __restrict__ bp1,
                                                 const float* __restrict__ bp2,
                                                 float* __restrict__ out,
                                                 int G, int relu) {
  __shared__ float xl[8 * 512];
  const int gr = blockIdx.x * 256 + threadIdx.x;
  const int t0 = blockIdx.y * 8;
  if (ids) {
    // embed-fused staging: 32 threads per row, float4 each
    const int r = threadIdx.x >> 5, e = threadIdx.x & 31;
    const long id = ids[63 * Tn + t0 + r];
    const float4* src = (const float4*)(tab + (size_t)id * En);
    ((float4*)&xl[r * 512])[e] = src[e];
    ((float4*)&xl[r * 512])[e + 32] = src[e + 32];
    ((float4*)&xl[r * 512])[e + 64] = src[e + 64];
    ((float4*)&xl[r * 512])[e + 96] = src[e + 96];
  } else {
    for (int i = threadIdx.x; i < 8 * 512; i += 256) xl[i] = A[(size_t)t0 * 512 + i];
  }
  __syncthreads();
  const float b = bp1[gr] + (bp2 ? bp2[gr] : 0.f);
  float acc[8];
#pragma unroll
  for (int tt = 0; tt < 8; tt++) acc[tt] = b;
  const float4* wr = (const float4*)(W + (size_t)gr * 512);
  for (int k4 = 0; k4 < 128; k4++) {
    const float4 w = wr[k4];
#pragma unroll
    for (int tt = 0; tt < 8; tt++) {
      const float4 xv = *(const float4*)&xl[tt * 512 + k4 * 4];
      acc[tt] = fmaf(w.x, xv.x, fmaf(w.y, xv.y, fmaf(w.z, xv.z, fmaf(w.w, xv.w, acc[tt]))));
    }
  }
#pragma unroll
  for (int tt = 0; tt < 8; tt++) {
    float v = acc[tt];
    if (relu) v = fmaxf(v, 0.f);
    out[(size_t)(t0 + tt) * G + gr] = v;
  }
}

// ---- bidirectional LSTM recurrence: R15 structure, tuned pacing ----
// Grid 128; workers b&7==0 (fwd) / ==1 (bwd); 16 WGs x 512 thr per domain,
// LDS pad -> 1 WG/CU. Agent/LLC exchange (only HIP-expressible path, R8-R14).
// R15 proven: pair-polling (120 pollers/WG, one dwordx4 probes 2 slots) +
// sleep-paced probes + naked lgkm barrier + role split. This round ONLY
// retunes the pacing: initial s_sleep 12->9 (~240ns; probe service then
// lands centered on the producer-visibility window), retry 6->3 (~80ns;
// halves average detect overshoot).
__global__ __launch_bounds__(512, 2) void rec_k(const float* __restrict__ xp,   // [T][2048] fwd|bwd
                                                float* __restrict__ hcat,       // [T][512]
                                                unsigned long long* __restrict__ ex, // [T][512]
                                                const float* __restrict__ whh,  // dir-major 2*1024*256
                                                unsigned stampbase) {
  __shared__ __align__(16) float hs[2][288];  // stride-36 chunks, double buffer
  __shared__ float pad[21000];                // forces 1 WG/CU (>80KB total)
  const int b = blockIdx.x;
  const int dir = b & 7;
  if (dir > 1) return;                 // 32 worker blocks, 96 exit
  const int wg = b >> 3;               // 0..15
  const int tid = threadIdx.x;
  const int lane = tid & 63;
  const int row = tid >> 3, kc = tid & 7;
  const int elem = row >> 2, gate = row & 3;
  const int he = wg * 16 + elem;        // global h element [0,256)
  const int gr = gate * 256 + he;       // gate row (i|f|g|o blocks of 256)
  const float* whhD = whh + (size_t)dir * 262144;
  const float* xpD = xp + dir * 1024;

  if (stampbase == 0xDEADBEEFu) {  // never true at runtime; keeps pad live
    pad[tid] = xp[tid];
    hcat[tid] = pad[tid ^ 1];
  }

  float4 q0, q1, q2, q3, q4, q5, q6, q7;
  {
    const float4* p = (const float4*)(whhD + (size_t)gr * 256 + kc * 32);
    q0 = p[0]; q1 = p[1]; q2 = p[2]; q3 = p[3];
    q4 = p[4]; q5 = p[5]; q6 = p[6]; q7 = p[7];
  }
  for (int i = tid; i < 2 * 288; i += 512) ((float*)hs)[i] = 0.f;
  float c = 0.f;
  float xv = 0.f;
  if (kc == 0) xv = xpD[(size_t)(dir ? (Tn - 1) : 0) * 2048 + gr];
  const int isprod = ((lane & 31) == 0);   // tid%32==0: 16 producers
  const int base = lane & 32;
  // pair-poller mapping: rank among non-producers; first 120 ranks poll the
  // 120 remote slot-PAIRS (own-WG 8 pairs self-staged by producers).
  const int pr = tid - 1 - (tid >> 5);
  const int ispoll = (!isprod) && (pr < 120);
  const int pairIdx = ispoll ? (pr + (pr >= wg * 8 ? 8 : 0)) : 0;
  const int s0 = 2 * pairIdx;                          // first slot of pair
  const int coff2 = (s0 >> 5) * 36 + (s0 & 31);        // both floats land here,+1
  const int poff = (he >> 5) * 36 + (he & 31);
  __syncthreads();  // init barrier (full drain, once)

  for (int t = 0; t < Tn; ++t) {
    const int p = t & 1;
    // matvec on hs[p] = h(t-1)
    const float4* h4 = (const float4*)&hs[p][kc * 36];
    const float4 h0 = h4[0], h1 = h4[1], h2 = h4[2], h3 = h4[3];
    const float4 h5 = h4[4], h6 = h4[5], h7 = h4[6], h8 = h4[7];
    float a = 0.f;
    a = fmaf(q0.x, h0.x, a); a = fmaf(q0.y, h0.y, a); a = fmaf(q0.z, h0.z, a); a = fmaf(q0.w, h0.w, a);
    a = fmaf(q1.x, h1.x, a); a = fmaf(q1.y, h1.y, a); a = fmaf(q1.z, h1.z, a); a = fmaf(q1.w, h1.w, a);
    a = fmaf(q2.x, h2.x, a); a = fmaf(q2.y, h2.y, a); a = fmaf(q2.z, h2.z, a); a = fmaf(q2.w, h2.w, a);
    a = fmaf(q3.x, h3.x, a); a = fmaf(q3.y, h3.y, a); a = fmaf(q3.z, h3.z, a); a = fmaf(q3.w, h3.w, a);
    a = fmaf(q4.x, h5.x, a); a = fmaf(q4.y, h5.y, a); a = fmaf(q4.z, h5.z, a); a = fmaf(q4.w, h5.w, a);
    a = fmaf(q5.x, h6.x, a); a = fmaf(q5.y, h6.y, a); a = fmaf(q5.z, h6.z, a); a = fmaf(q5.w, h6.w, a);
    a = fmaf(q6.x, h7.x, a); a = fmaf(q6.y, h7.y, a); a = fmaf(q6.z, h7.z, a); a = fmaf(q6.w, h7.w, a);
    a = fmaf(q7.x, h8.x, a); a = fmaf(q7.y, h8.y, a); a = fmaf(q7.z, h8.z, a); a = fmaf(q7.w, h8.w, a);
    a += __shfl_xor(a, 1);
    a += __shfl_xor(a, 2);
    a += __shfl_xor(a, 4);
    // kc==0 roots: add xproj and apply this gate's activation in parallel
    if (kc == 0) {
      a += xv;
      const float sg = 1.f / (1.f + __expf(-a));
      const float th = 1.f - 2.f / (1.f + __expf(2.f * a));
      a = (gate == 2) ? th : sg;
    }
    // gather the 4 ACTIVATED gates of this wave's two elements to lanes 0/32
    const float gi = __shfl(a, base + 0);
    const float gf = __shfl(a, base + 8);
    const float gg = __shfl(a, base + 16);
    const float go = __shfl(a, base + 24);
    if (isprod) {
      c = gf * c + gi * gg;
      const float hv = go * (1.f - 2.f / (1.f + __expf(2.f * c)));
      const unsigned long long word =
          ((unsigned long long)(stampbase + t + 1) << 32) | __float_as_uint(hv);
      // single agent store (fire-and-forget; ack floats across naked barrier)
      __hip_atomic_store(&ex[(size_t)t * 512 + dir * 256 + he], word,
                         __ATOMIC_RELAXED, __HIP_MEMORY_SCOPE_AGENT);
      hs[p ^ 1][poff] = hv;  // self-stage own element
      const int rowt = dir ? (Tn - 1 - t) : t;
      hcat[(size_t)rowt * 512 + dir * 256 + he] = hv;  // fire-and-forget
    } else if (ispoll && t + 1 < Tn) {
      const unsigned long long* pp = &ex[(size_t)t * 512 + dir * 256 + s0];
      const unsigned tgt = stampbase + (unsigned)t + 1u;
      typedef unsigned int u32x4 __attribute__((ext_vector_type(4)));
      u32x4 v;
      int tot = 0;
      asm volatile("s_sleep 9");    // ~240ns: probe service centered on visibility
      for (;;) {
        asm volatile("global_load_dwordx4 %0, %1, off sc0 sc1\n\ts_waitcnt vmcnt(0)"
                     : "=v"(v) : "v"(pp) : "memory");
        if (v.y == tgt && v.w == tgt) break;   // both pair stamps fresh
        if (++tot >= (1 << 18)) break;
        asm volatile("s_sleep 3");  // ~80ns pacing between probes
      }
      hs[p ^ 1][coff2]     = __uint_as_float(v.x);
      hs[p ^ 1][coff2 + 1] = __uint_as_float(v.z);
    }
    if (kc == 0 && t + 1 < Tn)  // xv prefetch AFTER poll; floats across barrier
      xv = xpD[(size_t)(dir ? (Tn - 2 - t) : (t + 1)) * 2048 + gr];
    // naked barrier: LDS ordering only, no vmcnt drain
    asm volatile("s_waitcnt lgkmcnt(0)\n\ts_barrier" ::: "memory");
  }
}

// ---- final 1024->7 matmul + softmax per timestep ----
__global__ __launch_bounds__(64) void mlp2_k(const float* __restrict__ h1,
                                             const float* __restrict__ w2,
                                             const float* __restrict__ b2,
                                             float* __restrict__ out) {
  __shared__ float hrow[1024];
  __shared__ float lg[8];
  const int t = blockIdx.x, tid = threadIdx.x;
  for (int i = tid; i < 1024; i += 64) hrow[i] = h1[(size_t)t * 1024 + i];
  __syncthreads();
  const int o = tid >> 3, kc = tid & 7;
  float acc = 0.f;
  if (o < 7) {
    const float* wv = w2 + (size_t)o * 1024 + kc * 128;
    const float* h = &hrow[kc * 128];
    for (int jj = 0; jj < 128; jj++) acc = fmaf(wv[jj], h[jj], acc);
  }
#pragma unroll
  for (int off = 1; off < 8; off <<= 1) acc += __shfl_xor(acc, off);
  if (o < 7 && kc == 0) lg[o] = acc + b2[o];
  __syncthreads();
  if (tid == 0) {
    float mx = -1e30f;
#pragma unroll
    for (int i = 0; i < 7; i++) mx = fmaxf(mx, lg[i]);
    float e[7];
    float s = 0.f;
#pragma unroll
    for (int i = 0; i < 7; i++) { e[i] = __expf(lg[i] - mx); s += e[i]; }
    const float inv = 1.f / s;
#pragma unroll
    for (int i = 0; i < 7; i++) out[t * 7 + i] = e[i] * inv;
  }
}

extern "C" void kernel_launch(void* const* d_in, const int* in_sizes, int n_in,
                              void* d_out, int out_size, void* d_ws, size_t ws_size,
                              hipStream_t stream) {
  const int* ids = (const int*)d_in[0];
  const float* tab = (const float*)d_in[1];
  const float* wih = (const float*)d_in[2];   // (2,2,1024,512)
  const float* whh = (const float*)d_in[3];   // (2,2,1024,256)
  const float* bih = (const float*)d_in[4];   // (2,2,1024)
  const float* bhh = (const float*)d_in[5];
  const float* w1 = (const float*)d_in[6];    // (1024,512)
  const float* b1 = (const float*)d_in[7];
  const float* w2 = (const float*)d_in[8];    // (7,1024)
  const float* b2 = (const float*)d_in[9];
  float* out = (float*)d_out;                 // (200,7) f32
  float* ws = (float*)d_ws;

  float* xp = ws + 102400;            // 200*2048 (reused both layers)
  float* h0 = ws + 512000;            // 200*512
  float* h1 = ws + 614400;            // 200*512
  float* hm = ws + 716800;            // 200*1024
  unsigned long long* ex = (unsigned long long*)(ws + 921600);  // 200*512 slots

  // clear stamps from previous replay (slots are write-once within a launch)
  hipMemsetAsync(ex, 0, (size_t)Tn * 512 * 8, stream);
  // layer 0 (embed gather fused into the xproj gemm)
  gemm_rows<<<dim3(8, 25), 256, 0, stream>>>(nullptr, ids, tab, wih, bih, bhh, xp, 2048, 0);
  rec_k<<<128, 512, 0, stream>>>(xp, h0, ex, whh, 0u);
  // layer 1 (shared ex buffer, disjoint stamp base)
  gemm_rows<<<dim3(8, 25), 256, 0, stream>>>(h0, nullptr, nullptr, wih + 1048576,
                                             bih + 2048, bhh + 2048, xp, 2048, 0);
  rec_k<<<128, 512, 0, stream>>>(xp, h1, ex, whh + 524288, 1000000u);
  // MLP
  gemm_rows<<<dim3(4, 25), 256, 0, stream>>>(h1, nullptr, nullptr, w1, b1, nullptr, hm, 1024, 1);
  mlp2_k<<<Tn, 64, 0, stream>>>(hm, w2, b2, out);
}